// Round 10
// baseline (241.998 us; speedup 1.0000x reference)
//
#include <hip/hip_runtime.h>
#include <math.h>

#define C 320
#define NPTS 2048
#define SUPPTS 20480   // 2*5*2048 support points
#define QPTS 4096      // 2*2048 query points
#define KP 100         // prototypes per problem
#define NCLS 3
#define PSTRIDE 300    // transposed proto row stride (floats)

// ---------------- kernel 1: fused seed-find + gather + self-norm -> pbufT[c][300] ----------------
// [verbatim r9, PASSED]
__global__ __launch_bounds__(64) void k_protoseed(const float* __restrict__ sup,
                                                  const int* __restrict__ sy,
                                                  float* __restrict__ pbufT) {
    int p    = blockIdx.x;     // 0..299
    int lane = threadIdx.x;
    int prob = (p < 100) ? 2 : ((p < 200) ? 0 : 1);
    int rank = (p < 100) ? p : ((p < 200) ? p - 100 : p - 200);
    int M    = (prob == 2) ? SUPPTS : 10240;
    int base = (prob == 1) ? 10240 : 0;
    int found = 0, sp = 0;
    for (int chunk = 0; chunk < M; chunk += 64) {
        int yy = sy[base + chunk + lane];
        int m  = (prob == 2) ? (1 - yy) : yy;
        unsigned long long bal = __ballot(m != 0);
        int cnt = __popcll(bal);
        if (found + cnt > rank) {
            int need = rank - found;
            int prefix = __popcll(bal & ((1ull << lane) - 1ull));
            unsigned long long match = __ballot(m && (prefix == need));
            int pos = __ffsll((unsigned long long)match) - 1;
            sp = base + chunk + pos;
            break;
        }
        found += cnt;
    }
    const float* fb = sup + ((size_t)(sp >> 11) * C) * NPTS + (sp & 2047);
    float v[5]; float s = 0.f;
    #pragma unroll
    for (int i = 0; i < 5; i++) {
        v[i] = fb[(size_t)(lane + i * 64) * NPTS];
        s += v[i] * v[i];
    }
    #pragma unroll
    for (int off = 32; off > 0; off >>= 1) s += __shfl_down(s, off);
    s = __shfl(s, 0);
    float r = 1.0f / (sqrtf(s) + 1e-8f);
    #pragma unroll
    for (int i = 0; i < 5; i++)
        pbufT[(size_t)(lane + i * 64) * PSTRIDE + p] = v[i] * r;
}

// ---------------- kernel 2: sim max, 8 pts/lane x 10 protos, dual-buffered global loads ----------------
// grid (80, 10), block 64. LDS-broadcast amortized over 8 points (P=8 cuts LDS issue time 4x vs r9).
// Channel accumulation order identical to r9 -> bit-exact assignments.
__global__ __launch_bounds__(64) void k_assign(const float* __restrict__ sup,
                                               const float* __restrict__ pbT,
                                               float* __restrict__ pmaxv,
                                               int* __restrict__ pmaxj) {
    __shared__ float shp[C * 16];          // 10 protos padded to 16/row (64B rows, broadcast reads)
    int b = blockIdx.x, jt = blockIdx.y, lane = threadIdx.x;
    int prob, pt, gbase, aoff;
    if (b < 20)      { prob = 0; pt = b * 512;        gbase = 0;     aoff = 0; }
    else if (b < 40) { prob = 1; pt = (b - 20) * 512; gbase = 10240; aoff = 10240; }
    else             { prob = 2; pt = (b - 40) * 512; gbase = 0;     aoff = 20480; }
    int j0 = jt * 10;
    int col0 = ((prob == 2) ? 0 : (100 + prob * 100)) + j0;
    for (int i = lane; i < C * 10; i += 64) {
        int j = i % 10, c = i / 10;
        shp[c * 16 + j] = pbT[(size_t)c * PSTRIDE + col0 + j];
    }
    __syncthreads();
    int g = gbase + pt + lane * 8;
    const float* fb = sup + ((size_t)(g >> 11) * C) * NPTS + (g & 2047);
    float acc[8][10];
    #pragma unroll
    for (int p = 0; p < 8; p++)
        #pragma unroll
        for (int j = 0; j < 10; j++) acc[p][j] = 0.f;
    float4 bufA[8], bufB[8];   // [2*k], [2*k+1] = pts 0-3, 4-7 of channel group k
    #pragma unroll
    for (int k = 0; k < 4; k++) {
        bufA[2*k]   = *(const float4*)(fb + (size_t)k * NPTS);
        bufA[2*k+1] = *(const float4*)(fb + (size_t)k * NPTS + 4);
    }
    for (int cc = 0; cc < C; cc += 8) {
        // prefetch ch cc+4..cc+7 into bufB
        #pragma unroll
        for (int k = 0; k < 4; k++) {
            int c = cc + 4 + k;
            bufB[2*k]   = *(const float4*)(fb + (size_t)c * NPTS);
            bufB[2*k+1] = *(const float4*)(fb + (size_t)c * NPTS + 4);
        }
        // FMA ch cc..cc+3 from bufA
        #pragma unroll
        for (int k = 0; k < 4; k++) {
            const float* row = &shp[(cc + k) * 16];
            float4 q0 = ((const float4*)row)[0];
            float4 q1 = ((const float4*)row)[1];
            float2 q2 = ((const float2*)row)[4];
            float pr[10] = {q0.x,q0.y,q0.z,q0.w,q1.x,q1.y,q1.z,q1.w,q2.x,q2.y};
            float4 lo = bufA[2*k], hi = bufA[2*k+1];
            float pv[8] = {lo.x,lo.y,lo.z,lo.w,hi.x,hi.y,hi.z,hi.w};
            #pragma unroll
            for (int p = 0; p < 8; p++)
                #pragma unroll
                for (int j = 0; j < 10; j++) acc[p][j] += pv[p] * pr[j];
        }
        // prefetch ch cc+8..cc+11 into bufA
        if (cc + 8 < C) {
            #pragma unroll
            for (int k = 0; k < 4; k++) {
                int c = cc + 8 + k;
                bufA[2*k]   = *(const float4*)(fb + (size_t)c * NPTS);
                bufA[2*k+1] = *(const float4*)(fb + (size_t)c * NPTS + 4);
            }
        }
        // FMA ch cc+4..cc+7 from bufB
        #pragma unroll
        for (int k = 0; k < 4; k++) {
            const float* row = &shp[(cc + 4 + k) * 16];
            float4 q0 = ((const float4*)row)[0];
            float4 q1 = ((const float4*)row)[1];
            float2 q2 = ((const float2*)row)[4];
            float pr[10] = {q0.x,q0.y,q0.z,q0.w,q1.x,q1.y,q1.z,q1.w,q2.x,q2.y};
            float4 lo = bufB[2*k], hi = bufB[2*k+1];
            float pv[8] = {lo.x,lo.y,lo.z,lo.w,hi.x,hi.y,hi.z,hi.w};
            #pragma unroll
            for (int p = 0; p < 8; p++)
                #pragma unroll
                for (int j = 0; j < 10; j++) acc[p][j] += pv[p] * pr[j];
        }
    }
    size_t base0 = (size_t)(aoff + pt + lane * 8) * 10 + jt;
    #pragma unroll
    for (int p = 0; p < 8; p++) {
        float bv = acc[p][0]; int bj = 0;
        #pragma unroll
        for (int j = 1; j < 10; j++) if (acc[p][j] > bv) { bv = acc[p][j]; bj = j; }
        pmaxv[base0 + (size_t)p * 10] = bv;
        pmaxj[base0 + (size_t)p * 10] = j0 + bj;
    }
}

// ---------------- kernel 3: combine 10 tiles -> per-point destination bin (0..299); init loss ----------------
// [verbatim r6-proposal, PASSED r7]
__global__ __launch_bounds__(256) void k_combine_dst(const float* __restrict__ pmaxv,
                                                     const int* __restrict__ pmaxj,
                                                     const int* __restrict__ sy,
                                                     int* __restrict__ dst,
                                                     float* __restrict__ loss) {
    int g = blockIdx.x * 256 + threadIdx.x;   // 0..20479
    if (g == 0) loss[0] = 0.f;
    float bvf = pmaxv[(size_t)g * 10]; int bjf = pmaxj[(size_t)g * 10];
    #pragma unroll
    for (int t = 1; t < 10; t++) {
        float v = pmaxv[(size_t)g * 10 + t];
        if (v > bvf) { bvf = v; bjf = pmaxj[(size_t)g * 10 + t]; }
    }
    size_t gb = (size_t)(SUPPTS + g) * 10;
    float bvb = pmaxv[gb]; int bjb = pmaxj[gb];
    #pragma unroll
    for (int t = 1; t < 10; t++) {
        float v = pmaxv[gb + t];
        if (v > bvb) { bvb = v; bjb = pmaxj[gb + t]; }
    }
    int way = (g >= 10240) ? 1 : 0;
    dst[g] = sy[g] ? (100 + way * 100 + bjf) : bjb;
}

// ---------------- kernel 4: LDS-binned accumulation. grid (20 slots, 40 ch-tiles of 8) ----------------
// [verbatim r9, PASSED]
__global__ __launch_bounds__(256) void k_accum_lds(const float* __restrict__ sup,
                                                   const int* __restrict__ dst,
                                                   float* __restrict__ part,
                                                   float* __restrict__ cnt) {
    __shared__ float bins[8 * 200];
    __shared__ float scnt[200];
    int bx = blockIdx.x;     // slot = ws*2 + half
    int ct = blockIdx.y;     // 0..39
    int tid = threadIdx.x;
    int ws = bx >> 1, half = bx & 1;
    int w = (ws >= 5) ? 1 : 0;
    int nbase = half * 1024;
    for (int i = tid; i < 8 * 200; i += 256) bins[i] = 0.f;
    if (ct == 0 && tid < 200) scnt[tid] = 0.f;
    int dreg[4];
    #pragma unroll
    for (int sub = 0; sub < 4; sub++) {
        int d = dst[ws * 2048 + nbase + sub * 256 + tid];
        dreg[sub] = (d < 100) ? d : (d - w * 100);   // local bin 0..199
    }
    __syncthreads();
    if (ct == 0) {
        #pragma unroll
        for (int sub = 0; sub < 4; sub++) atomicAdd(&scnt[dreg[sub]], 1.0f);
    }
    const float* base = sup + ((size_t)ws * C + ct * 8) * NPTS + nbase;
    for (int cl = 0; cl < 8; cl++) {
        const float* row = base + (size_t)cl * NPTS;
        #pragma unroll
        for (int sub = 0; sub < 4; sub++)
            atomicAdd(&bins[cl * 200 + dreg[sub]], row[sub * 256 + tid]);
    }
    __syncthreads();
    float* pout = part + (size_t)(bx * 40 + ct) * 1600;
    for (int i = tid; i < 8 * 200; i += 256) {
        int bin = i >> 3, cl = i & 7;
        pout[i] = bins[cl * 200 + bin];       // coalesced write, layout [bin][cl]
    }
    if (ct == 0 && tid < 200) cnt[bx * 200 + tid] = scnt[tid];
}

// ---------------- kernel 5: reduce partials + mean + l2norm -> phatT[c][300] ----------------
// [verbatim r9, PASSED]
__global__ __launch_bounds__(64) void k_reduce_proto(const float* __restrict__ part,
                                                     const float* __restrict__ cnt,
                                                     float* __restrict__ phatT) {
    int d   = blockIdx.x;    // 0..299
    int tid = threadIdx.x;
    int local, s0, ns;
    if (d < 100)      { local = d;       s0 = 0;  ns = 20; }
    else if (d < 200) { local = d;       s0 = 0;  ns = 10; }  // fg way0 (slots 0..9)
    else              { local = d - 100; s0 = 10; ns = 10; }  // fg way1 (slots 10..19)
    float dn = 0.f;
    for (int k = 0; k < ns; k++) dn += cnt[(s0 + k) * 200 + local];
    float inv = 1.0f / (dn + 1e-8f);
    float vals[5]; float sq = 0.f;
    #pragma unroll
    for (int i = 0; i < 5; i++) {
        int c = tid + i * 64;
        int ct = c >> 3, cl = c & 7;
        float s = 0.f;
        for (int k = 0; k < ns; k++)
            s += part[(size_t)((s0 + k) * 40 + ct) * 1600 + local * 8 + cl];
        float v = s * inv;
        vals[i] = v; sq += v * v;
    }
    #pragma unroll
    for (int off = 32; off > 0; off >>= 1) sq += __shfl_down(sq, off);
    sq = __shfl(sq, 0);
    float rn = 1.0f / (sqrtf(sq) + 1e-8f);
    #pragma unroll
    for (int i = 0; i < 5; i++)
        phatT[(size_t)(tid + i * 64) * PSTRIDE + d] = vals[i] * rn;
}

// ---------------- kernel 6: query sim max, split-channel 4 waves, + fused query norm ----------------
// grid (16, 30), block 256. [verbatim r9, PASSED]
__global__ __launch_bounds__(256) void k_qpartial(const float* __restrict__ qry,
                                                  const float* __restrict__ phT,
                                                  float* __restrict__ qmaxv,
                                                  float* __restrict__ qrn) {
    __shared__ float shp[C * 16];
    __shared__ float red[3 * 64 * 45];     // 40 accs + 4 qn partials, stride 45
    int pb = blockIdx.x, jt = blockIdx.y, tid = threadIdx.x;
    int wave = tid >> 6, lane = tid & 63;
    int j0 = jt * 10;
    for (int i = tid; i < C * 10; i += 256) {
        int j = i % 10, c = i / 10;
        shp[c * 16 + j] = phT[(size_t)c * PSTRIDE + j0 + j];
    }
    __syncthreads();
    int m = pb * 256 + lane * 4;    // 0..4095
    int c0 = wave * 80;
    const float* fb = qry + ((size_t)(m >> 11) * C + c0) * NPTS + (m & 2047);
    float acc[4][10];
    #pragma unroll
    for (int p = 0; p < 4; p++)
        #pragma unroll
        for (int j = 0; j < 10; j++) acc[p][j] = 0.f;
    float qn[4] = {0.f, 0.f, 0.f, 0.f};
    float4 pf[8];
    #pragma unroll
    for (int k = 0; k < 8; k++) pf[k] = *(const float4*)(fb + (size_t)k * NPTS);
    for (int cc = 0; cc < 80; cc += 8) {
        float4 cur[8];
        #pragma unroll
        for (int k = 0; k < 8; k++) cur[k] = pf[k];
        if (cc + 8 < 80) {
            #pragma unroll
            for (int k = 0; k < 8; k++) pf[k] = *(const float4*)(fb + (size_t)(cc + 8 + k) * NPTS);
        }
        #pragma unroll
        for (int k = 0; k < 8; k++) {
            const float* row = &shp[(c0 + cc + k) * 16];
            float4 p0 = ((const float4*)row)[0];
            float4 p1 = ((const float4*)row)[1];
            float2 p2 = ((const float2*)row)[4];
            float pr[10] = {p0.x,p0.y,p0.z,p0.w,p1.x,p1.y,p1.z,p1.w,p2.x,p2.y};
            float4 cv = cur[k];
            if (jt == 0) {
                qn[0] += cv.x*cv.x; qn[1] += cv.y*cv.y; qn[2] += cv.z*cv.z; qn[3] += cv.w*cv.w;
            }
            #pragma unroll
            for (int j = 0; j < 10; j++) {
                acc[0][j] += cv.x * pr[j];
                acc[1][j] += cv.y * pr[j];
                acc[2][j] += cv.z * pr[j];
                acc[3][j] += cv.w * pr[j];
            }
        }
    }
    if (wave > 0) {
        float* my = red + ((wave - 1) * 64 + lane) * 45;
        #pragma unroll
        for (int p = 0; p < 4; p++)
            #pragma unroll
            for (int j = 0; j < 10; j++) my[p * 10 + j] = acc[p][j];
        #pragma unroll
        for (int p = 0; p < 4; p++) my[40 + p] = qn[p];
    }
    __syncthreads();
    if (wave == 0) {
        #pragma unroll
        for (int w = 0; w < 3; w++) {
            const float* my = red + (w * 64 + lane) * 45;
            #pragma unroll
            for (int p = 0; p < 4; p++)
                #pragma unroll
                for (int j = 0; j < 10; j++) acc[p][j] += my[p * 10 + j];
            #pragma unroll
            for (int p = 0; p < 4; p++) qn[p] += my[40 + p];
        }
        #pragma unroll
        for (int p = 0; p < 4; p++) {
            float bv = acc[p][0];
            #pragma unroll
            for (int j = 1; j < 10; j++) bv = fmaxf(bv, acc[p][j]);
            qmaxv[(size_t)(m + p) * 30 + jt] = bv;
        }
        if (jt == 0) {
            #pragma unroll
            for (int p = 0; p < 4; p++) qrn[m + p] = 1.0f / (sqrtf(qn[p]) + 1e-8f);
        }
    }
}

// ---------------- kernel 7: per-class max, softmax CE, write pred ----------------
// [verbatim r9, PASSED]
__global__ __launch_bounds__(256) void k_pred(const float* __restrict__ qmaxv,
                                              const float* __restrict__ qrn,
                                              const int* __restrict__ qy,
                                              float* __restrict__ out,
                                              float* __restrict__ lossacc) {
    int m = blockIdx.x * 256 + threadIdx.x;  // 0..4095
    float rn = qrn[m];
    float pred[NCLS];
    #pragma unroll
    for (int cls = 0; cls < NCLS; cls++) {
        float g = qmaxv[(size_t)m * 30 + cls * 10];
        #pragma unroll
        for (int t = 1; t < 10; t++) g = fmaxf(g, qmaxv[(size_t)m * 30 + cls * 10 + t]);
        pred[cls] = rn * g;
    }
    int q = m >> 11, n = m & 2047;
    #pragma unroll
    for (int cls = 0; cls < NCLS; cls++)
        out[1 + ((size_t)(q * NCLS + cls)) * NPTS + n] = pred[cls];
    float mx = fmaxf(pred[0], fmaxf(pred[1], pred[2]));
    float lse = mx + logf(expf(pred[0] - mx) + expf(pred[1] - mx) + expf(pred[2] - mx));
    int lab = qy[m];
    atomicAdd(lossacc, lse - pred[lab]);   // = -log p[label]
}

// ---------------- kernel 8: final labels + loss. block 1024 ----------------
// [verbatim r9, PASSED]
__global__ __launch_bounds__(1024) void k_final(float* __restrict__ out,
                                                const float* __restrict__ lossacc) {
    __shared__ float red[1024];
    const float* pr = out + 1;
    int tid = threadIdx.x;
    float conf[4]; int lab[4];
    float s = 0.f;
    #pragma unroll
    for (int i = 0; i < 4; i++) {
        int m = tid + i * 1024;         // 0..4095
        int q = m >> 11, n = m & 2047;
        float p0 = pr[((size_t)(q * NCLS + 0)) * NPTS + n];
        float p1 = pr[((size_t)(q * NCLS + 1)) * NPTS + n];
        float p2 = pr[((size_t)(q * NCLS + 2)) * NPTS + n];
        int l = 0; float c = p0;
        if (p1 > c) { c = p1; l = 1; }
        if (p2 > c) { c = p2; l = 2; }
        conf[i] = c; lab[i] = l; s += c;
    }
    red[tid] = s; __syncthreads();
    for (int off = 512; off > 0; off >>= 1) {
        if (tid < off) red[tid] += red[tid + off];
        __syncthreads();
    }
    float mean = red[0] / (float)QPTS;
    #pragma unroll
    for (int i = 0; i < 4; i++) {
        int m = tid + i * 1024;
        out[1 + 2 * NCLS * NPTS + m] = (conf[i] > mean) ? (float)lab[i] : -1.0f;
    }
    if (tid == 0) out[0] = 2.0f * lossacc[0] / (float)QPTS;
}

extern "C" void kernel_launch(void* const* d_in, const int* in_sizes, int n_in,
                              void* d_out, int out_size, void* d_ws, size_t ws_size,
                              hipStream_t stream) {
    const float* sup = (const float*)d_in[0];   // [2,5,320,2048]
    const float* qry = (const float*)d_in[1];   // [2,320,2048]
    const int*   sy  = (const int*)d_in[2];     // [2,5,2048]
    const int*   qy  = (const int*)d_in[3];     // [2,2048]
    float* out = (float*)d_out;

    // workspace layout — persistent region, then transient overlay region
    float* f      = (float*)d_ws;
    float* qrn    = f;                     // 4096
    float* cnt    = qrn + QPTS;            // 4000
    float* pbufT  = cnt + 4000;            // 96000
    float* phatT  = pbufT + 96000;         // 96000
    float* loss   = phatT + 96000;         // 4 (padded)
    int*   dstb   = (int*)(loss + 4);      // 20480
    float* trans  = (float*)(dstb + SUPPTS);
    // phase A (assign+combine): pmaxv[409600] + pmaxj[409600]
    float* pmaxv  = trans;
    int*   pmaxj  = (int*)(pmaxv + 409600);
    // phase B (accum+reduce): part[1,280,000] overlays phase A
    float* part   = trans;
    // phase C (qpartial+pred): qmaxv[122880] overlays again
    float* qmaxv  = trans;

    k_protoseed<<<300, 64, 0, stream>>>(sup, sy, pbufT);
    {
        dim3 grid(80, 10);
        k_assign<<<grid, 64, 0, stream>>>(sup, pbufT, pmaxv, pmaxj);
    }
    k_combine_dst<<<80, 256, 0, stream>>>(pmaxv, pmaxj, sy, dstb, loss);
    {
        dim3 grid(20, 40);
        k_accum_lds<<<grid, 256, 0, stream>>>(sup, dstb, part, cnt);
    }
    k_reduce_proto<<<300, 64, 0, stream>>>(part, cnt, phatT);
    {
        dim3 grid(16, 30);
        k_qpartial<<<grid, 256, 0, stream>>>(qry, phatT, qmaxv, qrn);
    }
    k_pred<<<16, 256, 0, stream>>>(qmaxv, qrn, qy, out, loss);
    k_final<<<1, 1024, 0, stream>>>(out, loss);
}

// Round 11
// 237.039 us; speedup vs baseline: 1.0209x; 1.0209x over previous
//
#include <hip/hip_runtime.h>
#include <math.h>

#define C 320
#define NPTS 2048
#define SUPPTS 20480   // 2*5*2048 support points
#define QPTS 4096      // 2*2048 query points
#define KP 100         // prototypes per problem
#define NCLS 3
#define PSTRIDE 300    // transposed proto row stride (floats)

// ---------------- kernel 1: fused seed-find + gather + self-norm -> pbufT[c][300] ----------------
// [verbatim r9/r10, PASSED twice]
__global__ __launch_bounds__(64) void k_protoseed(const float* __restrict__ sup,
                                                  const int* __restrict__ sy,
                                                  float* __restrict__ pbufT) {
    int p    = blockIdx.x;     // 0..299
    int lane = threadIdx.x;
    int prob = (p < 100) ? 2 : ((p < 200) ? 0 : 1);
    int rank = (p < 100) ? p : ((p < 200) ? p - 100 : p - 200);
    int M    = (prob == 2) ? SUPPTS : 10240;
    int base = (prob == 1) ? 10240 : 0;
    int found = 0, sp = 0;
    for (int chunk = 0; chunk < M; chunk += 64) {
        int yy = sy[base + chunk + lane];
        int m  = (prob == 2) ? (1 - yy) : yy;
        unsigned long long bal = __ballot(m != 0);
        int cnt = __popcll(bal);
        if (found + cnt > rank) {
            int need = rank - found;
            int prefix = __popcll(bal & ((1ull << lane) - 1ull));
            unsigned long long match = __ballot(m && (prefix == need));
            int pos = __ffsll((unsigned long long)match) - 1;
            sp = base + chunk + pos;
            break;
        }
        found += cnt;
    }
    const float* fb = sup + ((size_t)(sp >> 11) * C) * NPTS + (sp & 2047);
    float v[5]; float s = 0.f;
    #pragma unroll
    for (int i = 0; i < 5; i++) {
        v[i] = fb[(size_t)(lane + i * 64) * NPTS];
        s += v[i] * v[i];
    }
    #pragma unroll
    for (int off = 32; off > 0; off >>= 1) s += __shfl_down(s, off);
    s = __shfl(s, 0);
    float r = 1.0f / (sqrtf(s) + 1e-8f);
    #pragma unroll
    for (int i = 0; i < 5; i++)
        pbufT[(size_t)(lane + i * 64) * PSTRIDE + p] = v[i] * r;
}

// ---------------- kernel 2: sim max, 2 pts/thread x 20-proto tile, 8-deep prefetch ----------------
// grid (160, 5), block 128. [r9 math verbatim; ONLY output layout transposed to [jt][point]]
__global__ __launch_bounds__(128) void k_assign(const float* __restrict__ sup,
                                                const float* __restrict__ pbT,
                                                float* __restrict__ pmaxv,
                                                int* __restrict__ pmaxj) {
    __shared__ float shp[C * 20];   // [c][j], j contiguous
    int b = blockIdx.x, jt = blockIdx.y, tid = threadIdx.x;
    int prob, pt, gbase, aoff;
    if (b < 40)       { prob = 0; pt = b * 256;         gbase = 0;     aoff = 0; }
    else if (b < 80)  { prob = 1; pt = (b - 40) * 256;  gbase = 10240; aoff = 10240; }
    else              { prob = 2; pt = (b - 80) * 256;  gbase = 0;     aoff = 20480; }
    int j0 = jt * 20;
    int col0 = (prob == 2) ? 0 : (100 + prob * 100);    // pbufT column base for this problem
    for (int i = tid; i < C * 20; i += 128) {
        int j = i % 20, c = i / 20;
        shp[i] = pbT[(size_t)c * PSTRIDE + col0 + j0 + j];
    }
    __syncthreads();
    int g = gbase + pt + tid * 2;
    const float* fb = sup + ((size_t)(g >> 11) * C) * NPTS + (g & 2047);
    float acc0[20], acc1[20];
    #pragma unroll
    for (int j = 0; j < 20; j++) { acc0[j] = 0.f; acc1[j] = 0.f; }
    float2 pf[8];
    #pragma unroll
    for (int k = 0; k < 8; k++) pf[k] = *(const float2*)(fb + (size_t)k * NPTS);
    for (int cc = 0; cc < C; cc += 8) {
        float2 cur[8];
        #pragma unroll
        for (int k = 0; k < 8; k++) cur[k] = pf[k];
        if (cc + 8 < C) {
            #pragma unroll
            for (int k = 0; k < 8; k++) pf[k] = *(const float2*)(fb + (size_t)(cc + 8 + k) * NPTS);
        }
        #pragma unroll
        for (int k = 0; k < 8; k++) {
            const float4* r = (const float4*)&shp[(cc + k) * 20];
            float4 a = r[0], d1 = r[1], d2 = r[2], d3 = r[3], d4 = r[4];
            float px = cur[k].x, py = cur[k].y;
            acc0[0]+=px*a.x;  acc1[0]+=py*a.x;  acc0[1]+=px*a.y;  acc1[1]+=py*a.y;
            acc0[2]+=px*a.z;  acc1[2]+=py*a.z;  acc0[3]+=px*a.w;  acc1[3]+=py*a.w;
            acc0[4]+=px*d1.x; acc1[4]+=py*d1.x; acc0[5]+=px*d1.y; acc1[5]+=py*d1.y;
            acc0[6]+=px*d1.z; acc1[6]+=py*d1.z; acc0[7]+=px*d1.w; acc1[7]+=py*d1.w;
            acc0[8]+=px*d2.x; acc1[8]+=py*d2.x; acc0[9]+=px*d2.y; acc1[9]+=py*d2.y;
            acc0[10]+=px*d2.z;acc1[10]+=py*d2.z;acc0[11]+=px*d2.w;acc1[11]+=py*d2.w;
            acc0[12]+=px*d3.x;acc1[12]+=py*d3.x;acc0[13]+=px*d3.y;acc1[13]+=py*d3.y;
            acc0[14]+=px*d3.z;acc1[14]+=py*d3.z;acc0[15]+=px*d3.w;acc1[15]+=py*d3.w;
            acc0[16]+=px*d4.x;acc1[16]+=py*d4.x;acc0[17]+=px*d4.y;acc1[17]+=py*d4.y;
            acc0[18]+=px*d4.z;acc1[18]+=py*d4.z;acc0[19]+=px*d4.w;acc1[19]+=py*d4.w;
        }
    }
    float bv0 = acc0[0]; int bj0 = 0;
    float bv1 = acc1[0]; int bj1 = 0;
    #pragma unroll
    for (int j = 1; j < 20; j++) {
        if (acc0[j] > bv0) { bv0 = acc0[j]; bj0 = j; }
        if (acc1[j] > bv1) { bv1 = acc1[j]; bj1 = j; }
    }
    // transposed layout [jt][point]: fully coalesced (consecutive lanes -> consecutive addrs)
    size_t a0 = (size_t)jt * 40960 + (aoff + pt + tid * 2);
    pmaxv[a0]     = bv0; pmaxj[a0]     = j0 + bj0;
    pmaxv[a0 + 1] = bv1; pmaxj[a0 + 1] = j0 + bj1;
}

// ---------------- kernel 3: combine 5 tiles -> per-point destination bin (0..299); init loss/csum ----------------
// coalesced reads over transposed pmax layout
__global__ __launch_bounds__(256) void k_combine_dst(const float* __restrict__ pmaxv,
                                                     const int* __restrict__ pmaxj,
                                                     const int* __restrict__ sy,
                                                     int* __restrict__ dst,
                                                     float* __restrict__ loss) {
    int g = blockIdx.x * 256 + threadIdx.x;   // 0..20479
    if (g == 0) loss[0] = 0.f;
    if (g == 1) loss[1] = 0.f;                // csum accumulator
    float bvf = pmaxv[g]; int bjf = pmaxj[g];
    #pragma unroll
    for (int t = 1; t < 5; t++) {
        float v = pmaxv[(size_t)t * 40960 + g];
        if (v > bvf) { bvf = v; bjf = pmaxj[(size_t)t * 40960 + g]; }
    }
    float bvb = pmaxv[SUPPTS + g]; int bjb = pmaxj[SUPPTS + g];
    #pragma unroll
    for (int t = 1; t < 5; t++) {
        float v = pmaxv[(size_t)t * 40960 + SUPPTS + g];
        if (v > bvb) { bvb = v; bjb = pmaxj[(size_t)t * 40960 + SUPPTS + g]; }
    }
    int way = (g >= 10240) ? 1 : 0;
    dst[g] = sy[g] ? (100 + way * 100 + bjf) : bjb;
}

// ---------------- kernel 4: LDS-binned accumulation, 4 parity copies. grid (20, 40) ----------------
__global__ __launch_bounds__(256) void k_accum_lds(const float* __restrict__ sup,
                                                   const int* __restrict__ dst,
                                                   float* __restrict__ part,
                                                   float* __restrict__ cnt) {
    __shared__ float bins[8 * 800];   // [cl][copy][bin]: cl*800 + copy*200 + bin
    __shared__ float scnt[800];       // [copy][bin]
    int bx = blockIdx.x;     // slot = ws*2 + half
    int ct = blockIdx.y;     // 0..39
    int tid = threadIdx.x;
    int copy = tid & 3;
    int ws = bx >> 1, half = bx & 1;
    int w = (ws >= 5) ? 1 : 0;
    int nbase = half * 1024;
    for (int i = tid; i < 8 * 800; i += 256) bins[i] = 0.f;
    if (ct == 0) { for (int i = tid; i < 800; i += 256) scnt[i] = 0.f; }
    int dreg[4];
    #pragma unroll
    for (int sub = 0; sub < 4; sub++) {
        int d = dst[ws * 2048 + nbase + sub * 256 + tid];
        dreg[sub] = (d < 100) ? d : (d - w * 100);   // local bin 0..199
    }
    __syncthreads();
    if (ct == 0) {
        #pragma unroll
        for (int sub = 0; sub < 4; sub++) atomicAdd(&scnt[copy * 200 + dreg[sub]], 1.0f);
    }
    const float* base = sup + ((size_t)ws * C + ct * 8) * NPTS + nbase;
    for (int cl = 0; cl < 8; cl++) {
        const float* row = base + (size_t)cl * NPTS;
        #pragma unroll
        for (int sub = 0; sub < 4; sub++)
            atomicAdd(&bins[cl * 800 + copy * 200 + dreg[sub]], row[sub * 256 + tid]);
    }
    __syncthreads();
    float* pout = part + (size_t)(bx * 40 + ct) * 1600;
    for (int i = tid; i < 8 * 200; i += 256) {
        int bin = i >> 3, cl = i & 7;
        float s = bins[cl * 800 + bin] + bins[cl * 800 + 200 + bin]
                + bins[cl * 800 + 400 + bin] + bins[cl * 800 + 600 + bin];
        pout[i] = s;                          // coalesced write, layout [bin][cl]
    }
    if (ct == 0 && tid < 200)
        cnt[bx * 200 + tid] = scnt[tid] + scnt[200 + tid] + scnt[400 + tid] + scnt[600 + tid];
}

// ---------------- kernel 5: reduce partials + mean + l2norm -> phatT[c][300] ----------------
// [verbatim r9/r10, PASSED twice]
__global__ __launch_bounds__(64) void k_reduce_proto(const float* __restrict__ part,
                                                     const float* __restrict__ cnt,
                                                     float* __restrict__ phatT) {
    int d   = blockIdx.x;    // 0..299
    int tid = threadIdx.x;
    int local, s0, ns;
    if (d < 100)      { local = d;       s0 = 0;  ns = 20; }
    else if (d < 200) { local = d;       s0 = 0;  ns = 10; }  // fg way0 (slots 0..9)
    else              { local = d - 100; s0 = 10; ns = 10; }  // fg way1 (slots 10..19)
    float dn = 0.f;
    for (int k = 0; k < ns; k++) dn += cnt[(s0 + k) * 200 + local];
    float inv = 1.0f / (dn + 1e-8f);
    float vals[5]; float sq = 0.f;
    #pragma unroll
    for (int i = 0; i < 5; i++) {
        int c = tid + i * 64;
        int ct = c >> 3, cl = c & 7;
        float s = 0.f;
        for (int k = 0; k < ns; k++)
            s += part[(size_t)((s0 + k) * 40 + ct) * 1600 + local * 8 + cl];
        float v = s * inv;
        vals[i] = v; sq += v * v;
    }
    #pragma unroll
    for (int off = 32; off > 0; off >>= 1) sq += __shfl_down(sq, off);
    sq = __shfl(sq, 0);
    float rn = 1.0f / (sqrtf(sq) + 1e-8f);
    #pragma unroll
    for (int i = 0; i < 5; i++)
        phatT[(size_t)(tid + i * 64) * PSTRIDE + d] = vals[i] * rn;
}

// ---------------- kernel 6: query sim max, split-channel 4 waves, + fused query norm ----------------
// grid (16, 30), block 256. [verbatim r9/r10, PASSED twice]
__global__ __launch_bounds__(256) void k_qpartial(const float* __restrict__ qry,
                                                  const float* __restrict__ phT,
                                                  float* __restrict__ qmaxv,
                                                  float* __restrict__ qrn) {
    __shared__ float shp[C * 16];
    __shared__ float red[3 * 64 * 45];     // 40 accs + 4 qn partials, stride 45
    int pb = blockIdx.x, jt = blockIdx.y, tid = threadIdx.x;
    int wave = tid >> 6, lane = tid & 63;
    int j0 = jt * 10;
    for (int i = tid; i < C * 10; i += 256) {
        int j = i % 10, c = i / 10;
        shp[c * 16 + j] = phT[(size_t)c * PSTRIDE + j0 + j];
    }
    __syncthreads();
    int m = pb * 256 + lane * 4;    // 0..4095
    int c0 = wave * 80;
    const float* fb = qry + ((size_t)(m >> 11) * C + c0) * NPTS + (m & 2047);
    float acc[4][10];
    #pragma unroll
    for (int p = 0; p < 4; p++)
        #pragma unroll
        for (int j = 0; j < 10; j++) acc[p][j] = 0.f;
    float qn[4] = {0.f, 0.f, 0.f, 0.f};
    float4 pf[8];
    #pragma unroll
    for (int k = 0; k < 8; k++) pf[k] = *(const float4*)(fb + (size_t)k * NPTS);
    for (int cc = 0; cc < 80; cc += 8) {
        float4 cur[8];
        #pragma unroll
        for (int k = 0; k < 8; k++) cur[k] = pf[k];
        if (cc + 8 < 80) {
            #pragma unroll
            for (int k = 0; k < 8; k++) pf[k] = *(const float4*)(fb + (size_t)(cc + 8 + k) * NPTS);
        }
        #pragma unroll
        for (int k = 0; k < 8; k++) {
            const float* row = &shp[(c0 + cc + k) * 16];
            float4 p0 = ((const float4*)row)[0];
            float4 p1 = ((const float4*)row)[1];
            float2 p2 = ((const float2*)row)[4];
            float pr[10] = {p0.x,p0.y,p0.z,p0.w,p1.x,p1.y,p1.z,p1.w,p2.x,p2.y};
            float4 cv = cur[k];
            if (jt == 0) {
                qn[0] += cv.x*cv.x; qn[1] += cv.y*cv.y; qn[2] += cv.z*cv.z; qn[3] += cv.w*cv.w;
            }
            #pragma unroll
            for (int j = 0; j < 10; j++) {
                acc[0][j] += cv.x * pr[j];
                acc[1][j] += cv.y * pr[j];
                acc[2][j] += cv.z * pr[j];
                acc[3][j] += cv.w * pr[j];
            }
        }
    }
    if (wave > 0) {
        float* my = red + ((wave - 1) * 64 + lane) * 45;
        #pragma unroll
        for (int p = 0; p < 4; p++)
            #pragma unroll
            for (int j = 0; j < 10; j++) my[p * 10 + j] = acc[p][j];
        #pragma unroll
        for (int p = 0; p < 4; p++) my[40 + p] = qn[p];
    }
    __syncthreads();
    if (wave == 0) {
        #pragma unroll
        for (int w = 0; w < 3; w++) {
            const float* my = red + (w * 64 + lane) * 45;
            #pragma unroll
            for (int p = 0; p < 4; p++)
                #pragma unroll
                for (int j = 0; j < 10; j++) acc[p][j] += my[p * 10 + j];
            #pragma unroll
            for (int p = 0; p < 4; p++) qn[p] += my[40 + p];
        }
        #pragma unroll
        for (int p = 0; p < 4; p++) {
            float bv = acc[p][0];
            #pragma unroll
            for (int j = 1; j < 10; j++) bv = fmaxf(bv, acc[p][j]);
            qmaxv[(size_t)(m + p) * 30 + jt] = bv;
        }
        if (jt == 0) {
            #pragma unroll
            for (int p = 0; p < 4; p++) qrn[m + p] = 1.0f / (sqrtf(qn[p]) + 1e-8f);
        }
    }
}

// ---------------- kernel 7: per-class max, softmax CE, write pred + conf/label staging ----------------
// block-reduced loss & conf-sum atomics (1 each per block)
__global__ __launch_bounds__(256) void k_pred(const float* __restrict__ qmaxv,
                                              const float* __restrict__ qrn,
                                              const int* __restrict__ qy,
                                              float* __restrict__ out,
                                              float* __restrict__ lossacc,
                                              float* __restrict__ cbuf,
                                              int* __restrict__ lbuf) {
    __shared__ float redL[256];
    __shared__ float redC[256];
    int tid = threadIdx.x;
    int m = blockIdx.x * 256 + tid;  // 0..4095
    float rn = qrn[m];
    float pred[NCLS];
    #pragma unroll
    for (int cls = 0; cls < NCLS; cls++) {
        float g = qmaxv[(size_t)m * 30 + cls * 10];
        #pragma unroll
        for (int t = 1; t < 10; t++) g = fmaxf(g, qmaxv[(size_t)m * 30 + cls * 10 + t]);
        pred[cls] = rn * g;
    }
    int q = m >> 11, n = m & 2047;
    #pragma unroll
    for (int cls = 0; cls < NCLS; cls++)
        out[1 + ((size_t)(q * NCLS + cls)) * NPTS + n] = pred[cls];
    float mx = fmaxf(pred[0], fmaxf(pred[1], pred[2]));
    float lse = mx + logf(expf(pred[0] - mx) + expf(pred[1] - mx) + expf(pred[2] - mx));
    int lab = 0; float cf = pred[0];
    if (pred[1] > cf) { cf = pred[1]; lab = 1; }
    if (pred[2] > cf) { cf = pred[2]; lab = 2; }
    cbuf[m] = cf; lbuf[m] = lab;
    redL[tid] = lse - pred[qy[m]];
    redC[tid] = cf;
    __syncthreads();
    for (int off = 128; off > 0; off >>= 1) {
        if (tid < off) { redL[tid] += redL[tid + off]; redC[tid] += redC[tid + off]; }
        __syncthreads();
    }
    if (tid == 0) {
        atomicAdd(&lossacc[0], redL[0]);
        atomicAdd(&lossacc[1], redC[0]);
    }
}

// ---------------- kernel 8: final labels + loss. grid 16 x 256, fully coalesced ----------------
__global__ __launch_bounds__(256) void k_final(const float* __restrict__ cbuf,
                                               const int* __restrict__ lbuf,
                                               const float* __restrict__ lossacc,
                                               float* __restrict__ out) {
    int m = blockIdx.x * 256 + threadIdx.x;   // 0..4095
    float mean = lossacc[1] / (float)QPTS;
    float cf = cbuf[m];
    out[1 + 2 * NCLS * NPTS + m] = (cf > mean) ? (float)lbuf[m] : -1.0f;
    if (m == 0) out[0] = 2.0f * lossacc[0] / (float)QPTS;
}

extern "C" void kernel_launch(void* const* d_in, const int* in_sizes, int n_in,
                              void* d_out, int out_size, void* d_ws, size_t ws_size,
                              hipStream_t stream) {
    const float* sup = (const float*)d_in[0];   // [2,5,320,2048]
    const float* qry = (const float*)d_in[1];   // [2,320,2048]
    const int*   sy  = (const int*)d_in[2];     // [2,5,2048]
    const int*   qy  = (const int*)d_in[3];     // [2,2048]
    float* out = (float*)d_out;

    // workspace layout — persistent region, then transient overlay region
    float* f      = (float*)d_ws;
    float* qrn    = f;                     // 4096
    float* cnt    = qrn + QPTS;            // 4000
    float* pbufT  = cnt + 4000;            // 96000
    float* phatT  = pbufT + 96000;         // 96000
    float* loss   = phatT + 96000;         // 4 (loss[0], csum=loss[1])
    int*   dstb   = (int*)(loss + 4);      // 20480
    float* trans  = (float*)(dstb + SUPPTS);
    // phase A (assign+combine): pmaxv[204800] + pmaxj[204800], layout [5][40960]
    float* pmaxv  = trans;
    int*   pmaxj  = (int*)(pmaxv + 204800);
    // phase B (accum+reduce): part[1,280,000] overlays phase A
    float* part   = trans;
    // phase C (qpartial..final): qmaxv[122880] + cbuf[4096] + lbuf[4096] overlays again
    float* qmaxv  = trans;
    float* cbuf   = qmaxv + 122880;
    int*   lbuf   = (int*)(cbuf + QPTS);

    k_protoseed<<<300, 64, 0, stream>>>(sup, sy, pbufT);
    {
        dim3 grid(160, 5);
        k_assign<<<grid, 128, 0, stream>>>(sup, pbufT, pmaxv, pmaxj);
    }
    k_combine_dst<<<80, 256, 0, stream>>>(pmaxv, pmaxj, sy, dstb, loss);
    {
        dim3 grid(20, 40);
        k_accum_lds<<<grid, 256, 0, stream>>>(sup, dstb, part, cnt);
    }
    k_reduce_proto<<<300, 64, 0, stream>>>(part, cnt, phatT);
    {
        dim3 grid(16, 30);
        k_qpartial<<<grid, 256, 0, stream>>>(qry, phatT, qmaxv, qrn);
    }
    k_pred<<<16, 256, 0, stream>>>(qmaxv, qrn, qy, out, loss, cbuf, lbuf);
    k_final<<<16, 256, 0, stream>>>(cbuf, lbuf, loss, out);
}